// Round 2
// baseline (481.441 us; speedup 1.0000x reference)
//
#include <hip/hip_runtime.h>
#include <hip/hip_bf16.h>

#define B_ 8
#define N_ 2048
#define D_ 128

typedef __bf16 bf16_t;
typedef __bf16 v8bf __attribute__((ext_vector_type(8)));
typedef float  v4f  __attribute__((ext_vector_type(4)));

// ---------------------------------------------------------------------------
// k_prep: WT[o][i] = (bf16)Ww[i][o]; AT[o][i] = (bf16)Aw[i][o].
// ---------------------------------------------------------------------------
__global__ __launch_bounds__(256) void k_prep(
    const float* __restrict__ Ww, const float* __restrict__ Aw,
    bf16_t* __restrict__ WT, bf16_t* __restrict__ AT)
{
    int idx = blockIdx.x * 256 + threadIdx.x;   // 0..16383
    int o = idx >> 7, i = idx & 127;
    WT[idx] = (bf16_t)Ww[i * D_ + o];
    AT[idx] = (bf16_t)Aw[i * D_ + o];
}

// ---------------------------------------------------------------------------
// k_hg (MFMA): h = x@W + b; g = h@A.  Block = 64 rows, 4 waves x 16 rows.
// ---------------------------------------------------------------------------
__global__ __launch_bounds__(256) void k_hg(
    const float* __restrict__ x, const float* __restrict__ Wb,
    const bf16_t* __restrict__ WT, const bf16_t* __restrict__ AT,
    bf16_t* __restrict__ hb, bf16_t* __restrict__ gb)
{
    int wave = threadIdx.x >> 6;
    int lane = threadIdx.x & 63;
    int q = lane >> 4;
    int c = lane & 15;
    int nrow0 = blockIdx.x * 64 + wave * 16;    // global flat row (b*N+n)

    __shared__ float pw_all[4][16][132];
    float (*pw)[132] = pw_all[wave];

    v8bf ax[4];
#pragma unroll
    for (int kc = 0; kc < 4; ++kc) {
        const float* src = x + (size_t)(nrow0 + c) * D_ + kc * 32 + q * 8;
        float4 f0 = *(const float4*)src;
        float4 f1 = *(const float4*)(src + 4);
        v8bf a;
        a[0]=(bf16_t)f0.x; a[1]=(bf16_t)f0.y; a[2]=(bf16_t)f0.z; a[3]=(bf16_t)f0.w;
        a[4]=(bf16_t)f1.x; a[5]=(bf16_t)f1.y; a[6]=(bf16_t)f1.z; a[7]=(bf16_t)f1.w;
        ax[kc] = a;
    }

#pragma unroll
    for (int ct = 0; ct < 8; ++ct) {
        float bias = Wb[ct * 16 + c];
        v4f acc = {bias, bias, bias, bias};
#pragma unroll
        for (int kc = 0; kc < 4; ++kc) {
            v8bf bw = *(const v8bf*)(WT + (size_t)(ct * 16 + c) * D_ + kc * 32 + q * 8);
            acc = __builtin_amdgcn_mfma_f32_16x16x32_bf16(ax[kc], bw, acc, 0, 0, 0);
        }
#pragma unroll
        for (int r = 0; r < 4; ++r) pw[q * 4 + r][ct * 16 + c] = acc[r];
    }
    __builtin_amdgcn_wave_barrier();

    v8bf ahf[4];
#pragma unroll
    for (int kc = 0; kc < 4; ++kc) {
        v4f p0 = *(const v4f*)&pw[c][kc * 32 + q * 8];
        v4f p1 = *(const v4f*)&pw[c][kc * 32 + q * 8 + 4];
        v8bf a;
#pragma unroll
        for (int j = 0; j < 4; ++j) { a[j] = (bf16_t)p0[j]; a[j+4] = (bf16_t)p1[j]; }
        ahf[kc] = a;
    }
    {
        int row = lane >> 2, seg = lane & 3;
#pragma unroll
        for (int v = 0; v < 4; ++v) {
            v8bf hv;
#pragma unroll
            for (int j = 0; j < 8; ++j) hv[j] = (bf16_t)pw[row][seg * 32 + v * 8 + j];
            *(v8bf*)(hb + (size_t)(nrow0 + row) * D_ + seg * 32 + v * 8) = hv;
        }
    }
    __builtin_amdgcn_wave_barrier();

#pragma unroll
    for (int ct = 0; ct < 8; ++ct) {
        v4f acc = {0.f, 0.f, 0.f, 0.f};
#pragma unroll
        for (int kc = 0; kc < 4; ++kc) {
            v8bf bw = *(const v8bf*)(AT + (size_t)(ct * 16 + c) * D_ + kc * 32 + q * 8);
            acc = __builtin_amdgcn_mfma_f32_16x16x32_bf16(ahf[kc], bw, acc, 0, 0, 0);
        }
#pragma unroll
        for (int r = 0; r < 4; ++r) pw[q * 4 + r][ct * 16 + c] = acc[r];
    }
    __builtin_amdgcn_wave_barrier();
    {
        int row = lane >> 2, seg = lane & 3;
#pragma unroll
        for (int v = 0; v < 4; ++v) {
            v8bf gv;
#pragma unroll
            for (int j = 0; j < 8; ++j) gv[j] = (bf16_t)pw[row][seg * 32 + v * 8 + j];
            *(v8bf*)(gb + (size_t)(nrow0 + row) * D_ + seg * 32 + v * 8) = gv;
        }
    }
}

// ---------------------------------------------------------------------------
// k_att v3: round-0 structure (LDS transpose + 16B coalesced Pt stores —
// partial-line stores cost 2x WRITE_SIZE, measured r1), but LDS staged in
// bf16: eb = 4x64x72x2B = 36.9 KB (was 68 KB f32) -> 4 blocks/CU (16
// waves/CU, 50% occ cap) with VGPR=112 <= 128 -> launch_bounds(256,4).
// Pack phase: direct ds_read_b128 + 16B store (no convert).
// ---------------------------------------------------------------------------
__global__ __launch_bounds__(256, 4) void k_att(
    const bf16_t* __restrict__ hb, const bf16_t* __restrict__ gb,
    const float* __restrict__ adj, float* __restrict__ colsum,
    bf16_t* __restrict__ Pt)
{
    int bid = blockIdx.x;
    int b = bid & 7;
    int rest = bid >> 3;          // 0..255
    int nblk = rest >> 3;         // 0..31
    int mgrp = rest & 7;          // 0..7
    int wave = threadIdx.x >> 6;
    int lane = threadIdx.x & 63;
    int q = lane >> 4;
    int c = lane & 15;
    int nbase = nblk * 64;
    int mwav = mgrp * 256 + wave * 64;
    const size_t hgoff = (size_t)b * N_ * D_;
    const float* adjb = adj + (size_t)b * N_ * N_;

    __shared__ bf16_t eb_all[4][64][72];
    bf16_t (*eb)[72] = eb_all[wave];

    // A-frags: 4 n-subtiles (persistent)
    v8bf ag[4][4], ah[4][4];
#pragma unroll
    for (int sub = 0; sub < 4; ++sub)
#pragma unroll
        for (int kc = 0; kc < 4; ++kc) {
            size_t off = hgoff + (size_t)(nbase + sub * 16 + c) * D_ + kc * 32 + q * 8;
            ag[sub][kc] = *(const v8bf*)(gb + off);
            ah[sub][kc] = *(const v8bf*)(hb + off);
        }

    for (int t = 0; t < 4; ++t) {
        int mt = mwav + t * 16;
        // adj values: issue early, 16 independent 4B loads
        float av[4][4];
#pragma unroll
        for (int sub = 0; sub < 4; ++sub)
#pragma unroll
            for (int r = 0; r < 4; ++r)
                av[sub][r] = adjb[(size_t)(nbase + sub * 16 + q * 4 + r) * N_ + mt + c];
        // B-frags: 8 independent 16B loads
        v8bf bh[4], bg[4];
#pragma unroll
        for (int kc = 0; kc < 4; ++kc) {
            size_t off = hgoff + (size_t)(mt + c) * D_ + kc * 32 + q * 8;
            bh[kc] = *(const v8bf*)(hb + off);
            bg[kc] = *(const v8bf*)(gb + off);
        }
        v4f e[4];
#pragma unroll
        for (int sub = 0; sub < 4; ++sub) e[sub] = (v4f){0.f, 0.f, 0.f, 0.f};
#pragma unroll
        for (int kc = 0; kc < 4; ++kc)
#pragma unroll
            for (int sub = 0; sub < 4; ++sub) {
                e[sub] = __builtin_amdgcn_mfma_f32_16x16x32_bf16(ag[sub][kc], bh[kc], e[sub], 0, 0, 0);
                e[sub] = __builtin_amdgcn_mfma_f32_16x16x32_bf16(ah[sub][kc], bg[kc], e[sub], 0, 0, 0);
            }
        float cs = 0.f;
#pragma unroll
        for (int sub = 0; sub < 4; ++sub)
#pragma unroll
            for (int r = 0; r < 4; ++r) {
                float ex = __expf(e[sub][r]);
                float pv = (av[sub][r] > 0.f) ? ex : 0.f;
                eb[sub * 16 + q * 4 + r][t * 16 + c] = (bf16_t)pv;
                cs += pv;
            }
        cs += __shfl_xor(cs, 16);
        cs += __shfl_xor(cs, 32);
        if (lane < 16) atomicAdd(&colsum[b * N_ + mt + lane], cs);
    }
    __builtin_amdgcn_wave_barrier();
    // 64n x 64m bf16 tile -> coalesced 16B stores (full 64B lines per row pair)
    int prow = lane >> 3, pseg = lane & 7;
#pragma unroll
    for (int pass = 0; pass < 8; ++pass) {
        int row = pass * 8 + prow;
        v8bf o = *(const v8bf*)&eb[row][pseg * 8];
        *(v8bf*)(Pt + ((size_t)b * N_ + nbase + row) * N_ + mwav + pseg * 8) = o;
    }
}

// ---------------------------------------------------------------------------
// k_scaleT: hbTs[b][d][m] = h[b][m][d] * inv(colsum[b][m]).
// ---------------------------------------------------------------------------
__global__ __launch_bounds__(256) void k_scaleT(
    const bf16_t* __restrict__ hb, const float* __restrict__ colsum,
    bf16_t* __restrict__ hbTs)
{
    int bid = blockIdx.x;
    int b = bid >> 6;
    int rem = bid & 63;
    int nblk = rem >> 1;
    int dblk = rem & 1;
    int tid = threadIdx.x;
    __shared__ bf16_t sm[64][72];
    __shared__ float sinv[64];
    int n0 = nblk * 64, d0 = dblk * 64;
    int r = tid >> 3, cg = tid & 7;
#pragma unroll
    for (int rr = 0; rr < 2; ++rr) {
        int row = r + rr * 32;
        *(v8bf*)&sm[row][cg * 8] =
            *(const v8bf*)(hb + (size_t)(b * N_ + n0 + row) * D_ + d0 + cg * 8);
    }
    if (tid < 64) {
        float s = colsum[b * N_ + n0 + tid];
        sinv[tid] = (s > 0.f) ? 1.f / s : 0.f;
    }
    __syncthreads();
#pragma unroll
    for (int rr = 0; rr < 2; ++rr) {
        int dr = r + rr * 32;
        v8bf v;
#pragma unroll
        for (int jj = 0; jj < 8; ++jj)
            v[jj] = (bf16_t)((float)sm[cg * 8 + jj][dr] * sinv[cg * 8 + jj]);
        *(v8bf*)(hbTs + (size_t)(b * D_ + d0 + dr) * N_ + n0 + cg * 8) = v;
    }
}

// ---------------------------------------------------------------------------
// k_out v3: round-0 high-intensity structure (wave = m-octant, 32 MFMA /
// 12 loads per chunk), but the 8-round serialized combine is replaced by
// wave0 plain stores + 7 waves of concurrent LDS atomicAdd (ds_add_f32,
// (q*16+c)%32 bank pattern = 2-way = free). 2 barriers instead of 8.
// ---------------------------------------------------------------------------
__global__ __launch_bounds__(512, 2) void k_out(
    const bf16_t* __restrict__ Pt, const bf16_t* __restrict__ hbTs,
    const float* __restrict__ x, const float* __restrict__ gw,
    const float* __restrict__ gbias, float* __restrict__ out)
{
    int bid = blockIdx.x;
    int b = bid & 7;
    int nblk = bid >> 3;          // 0..31
    int tid = threadIdx.x;
    int wave = tid >> 6;          // m-octant
    int lane = tid & 63;
    int q = lane >> 4;
    int c = lane & 15;
    int nbase = nblk * 64;
    int m0 = wave * 256;

    __shared__ float hp[64][132];

    const bf16_t* hTb = hbTs + (size_t)b * D_ * N_;
    const bf16_t* Pb  = Pt + (size_t)b * N_ * N_;

    v4f acc[4][8];
#pragma unroll
    for (int sub = 0; sub < 4; ++sub)
#pragma unroll
        for (int dt = 0; dt < 8; ++dt) acc[sub][dt] = (v4f){0.f, 0.f, 0.f, 0.f};

    for (int ch = 0; ch < 8; ++ch) {
        int mch = m0 + ch * 32;
        v8bf a[4];
#pragma unroll
        for (int sub = 0; sub < 4; ++sub)
            a[sub] = *(const v8bf*)(Pb + (size_t)(nbase + sub * 16 + c) * N_ + mch + q * 8);
        v8bf vt[8];
#pragma unroll
        for (int dt = 0; dt < 8; ++dt)
            vt[dt] = *(const v8bf*)(hTb + (size_t)(dt * 16 + c) * N_ + mch + q * 8);
#pragma unroll
        for (int dt = 0; dt < 8; ++dt)
#pragma unroll
            for (int sub = 0; sub < 4; ++sub)
                acc[sub][dt] = __builtin_amdgcn_mfma_f32_16x16x32_bf16(a[sub], vt[dt], acc[sub][dt], 0, 0, 0);
    }

    // combine the 8 m-octants: wave0 stores, waves 1..7 concurrent ds_add_f32
    if (wave == 0) {
#pragma unroll
        for (int sub = 0; sub < 4; ++sub)
#pragma unroll
            for (int dt = 0; dt < 8; ++dt)
#pragma unroll
                for (int r = 0; r < 4; ++r)
                    hp[sub * 16 + q * 4 + r][dt * 16 + c] = acc[sub][dt][r];
    }
    __syncthreads();
    if (wave != 0) {
#pragma unroll
        for (int sub = 0; sub < 4; ++sub)
#pragma unroll
            for (int dt = 0; dt < 8; ++dt)
#pragma unroll
                for (int r = 0; r < 4; ++r)
                    atomicAdd(&hp[sub * 16 + q * 4 + r][dt * 16 + c], acc[sub][dt][r]);
    }
    __syncthreads();

    // fused epilogue: 512 thr = 64 rows x 8 segs x 16 d
    int row = tid >> 3;
    int seg = tid & 7;
    size_t g = (size_t)b * N_ + nbase + row;
    const float* xr = x + g * D_ + seg * 16;
    float xv[16], hv[16];
#pragma unroll
    for (int j = 0; j < 16; j += 4) {
        float4 f = *(const float4*)(xr + j);
        xv[j] = f.x; xv[j+1] = f.y; xv[j+2] = f.z; xv[j+3] = f.w;
    }
#pragma unroll
    for (int j = 0; j < 16; ++j) hv[j] = fmaxf(hp[row][seg * 16 + j], 0.f);
    float part = 0.f;
#pragma unroll
    for (int j = 0; j < 16; ++j)
        part += xv[j] * gw[seg * 16 + j] + hv[j] * gw[D_ + seg * 16 + j];
    part += __shfl_xor(part, 1);
    part += __shfl_xor(part, 2);
    part += __shfl_xor(part, 4);
    float coeff = 1.f / (1.f + __expf(-(part + gbias[0])));
    float* orow = out + g * D_ + seg * 16;
#pragma unroll
    for (int j = 0; j < 16; j += 4) {
        float4 o;
        o.x = coeff * xv[j]   + (1.f - coeff) * hv[j];
        o.y = coeff * xv[j+1] + (1.f - coeff) * hv[j+1];
        o.z = coeff * xv[j+2] + (1.f - coeff) * hv[j+2];
        o.w = coeff * xv[j+3] + (1.f - coeff) * hv[j+3];
        *(float4*)(orow + j) = o;
    }
}

// ---------------------------------------------------------------------------
extern "C" void kernel_launch(void* const* d_in, const int* in_sizes, int n_in,
                              void* d_out, int out_size, void* d_ws, size_t ws_size,
                              hipStream_t stream)
{
    const float* x     = (const float*)d_in[0];
    const float* adj   = (const float*)d_in[1];
    const float* Ww    = (const float*)d_in[2];
    const float* Wb    = (const float*)d_in[3];
    const float* Aw    = (const float*)d_in[4];
    const float* gw    = (const float*)d_in[5];
    const float* gbias = (const float*)d_in[6];
    float* out = (float*)d_out;

    char* ws = (char*)d_ws;
    bf16_t* hb     = (bf16_t*)(ws);                          // 4 MB
    bf16_t* gb     = (bf16_t*)(ws + (4 << 20));              // 4 MB
    bf16_t* hbTs   = (bf16_t*)(ws + (8 << 20));              // 4 MB
    float*  colsum = (float*)(ws + (12 << 20));              // 64 KB
    bf16_t* Pt     = (bf16_t*)(ws + (17 << 20));             // 64 MB
    bf16_t* WT     = (bf16_t*)(ws + (81 << 20));             // 32 KB
    bf16_t* AT     = (bf16_t*)(ws + (81 << 20) + (32 << 10));// 32 KB

    hipMemsetAsync(colsum, 0, B_ * N_ * sizeof(float), stream);
    k_prep<<<64, 256, 0, stream>>>(Ww, Aw, WT, AT);
    k_hg<<<B_ * N_ / 64, 256, 0, stream>>>(x, Wb, WT, AT, hb, gb);
    k_att<<<2048, 256, 0, stream>>>(hb, gb, adj, colsum, Pt);
    k_scaleT<<<512, 256, 0, stream>>>(hb, colsum, hbTs);
    k_out<<<256, 512, 0, stream>>>(Pt, hbTs, x, gw, gbias, out);
}

// Round 3
// 322.358 us; speedup vs baseline: 1.4935x; 1.4935x over previous
//
#include <hip/hip_runtime.h>
#include <hip/hip_bf16.h>

#define B_ 8
#define N_ 2048
#define D_ 128

typedef __bf16 bf16_t;
typedef __bf16 v8bf __attribute__((ext_vector_type(8)));
typedef float  v4f  __attribute__((ext_vector_type(4)));

// ---------------------------------------------------------------------------
// k_prep: WT[o][i] = (bf16)Ww[i][o]; AT[o][i] = (bf16)Aw[i][o].
// ---------------------------------------------------------------------------
__global__ __launch_bounds__(256) void k_prep(
    const float* __restrict__ Ww, const float* __restrict__ Aw,
    bf16_t* __restrict__ WT, bf16_t* __restrict__ AT)
{
    int idx = blockIdx.x * 256 + threadIdx.x;   // 0..16383
    int o = idx >> 7, i = idx & 127;
    WT[idx] = (bf16_t)Ww[i * D_ + o];
    AT[idx] = (bf16_t)Aw[i * D_ + o];
}

// ---------------------------------------------------------------------------
// k_hg (MFMA): h = x@W + b; g = h@A.  Block = 64 rows, 4 waves x 16 rows.
// ---------------------------------------------------------------------------
__global__ __launch_bounds__(256) void k_hg(
    const float* __restrict__ x, const float* __restrict__ Wb,
    const bf16_t* __restrict__ WT, const bf16_t* __restrict__ AT,
    bf16_t* __restrict__ hb, bf16_t* __restrict__ gb)
{
    int wave = threadIdx.x >> 6;
    int lane = threadIdx.x & 63;
    int q = lane >> 4;
    int c = lane & 15;
    int nrow0 = blockIdx.x * 64 + wave * 16;    // global flat row (b*N+n)

    __shared__ float pw_all[4][16][132];
    float (*pw)[132] = pw_all[wave];

    v8bf ax[4];
#pragma unroll
    for (int kc = 0; kc < 4; ++kc) {
        const float* src = x + (size_t)(nrow0 + c) * D_ + kc * 32 + q * 8;
        float4 f0 = *(const float4*)src;
        float4 f1 = *(const float4*)(src + 4);
        v8bf a;
        a[0]=(bf16_t)f0.x; a[1]=(bf16_t)f0.y; a[2]=(bf16_t)f0.z; a[3]=(bf16_t)f0.w;
        a[4]=(bf16_t)f1.x; a[5]=(bf16_t)f1.y; a[6]=(bf16_t)f1.z; a[7]=(bf16_t)f1.w;
        ax[kc] = a;
    }

#pragma unroll
    for (int ct = 0; ct < 8; ++ct) {
        float bias = Wb[ct * 16 + c];
        v4f acc = {bias, bias, bias, bias};
#pragma unroll
        for (int kc = 0; kc < 4; ++kc) {
            v8bf bw = *(const v8bf*)(WT + (size_t)(ct * 16 + c) * D_ + kc * 32 + q * 8);
            acc = __builtin_amdgcn_mfma_f32_16x16x32_bf16(ax[kc], bw, acc, 0, 0, 0);
        }
#pragma unroll
        for (int r = 0; r < 4; ++r) pw[q * 4 + r][ct * 16 + c] = acc[r];
    }
    __builtin_amdgcn_wave_barrier();

    v8bf ahf[4];
#pragma unroll
    for (int kc = 0; kc < 4; ++kc) {
        v4f p0 = *(const v4f*)&pw[c][kc * 32 + q * 8];
        v4f p1 = *(const v4f*)&pw[c][kc * 32 + q * 8 + 4];
        v8bf a;
#pragma unroll
        for (int j = 0; j < 4; ++j) { a[j] = (bf16_t)p0[j]; a[j+4] = (bf16_t)p1[j]; }
        ahf[kc] = a;
    }
    {
        int row = lane >> 2, seg = lane & 3;
#pragma unroll
        for (int v = 0; v < 4; ++v) {
            v8bf hv;
#pragma unroll
            for (int j = 0; j < 8; ++j) hv[j] = (bf16_t)pw[row][seg * 32 + v * 8 + j];
            *(v8bf*)(hb + (size_t)(nrow0 + row) * D_ + seg * 32 + v * 8) = hv;
        }
    }
    __builtin_amdgcn_wave_barrier();

#pragma unroll
    for (int ct = 0; ct < 8; ++ct) {
        v4f acc = {0.f, 0.f, 0.f, 0.f};
#pragma unroll
        for (int kc = 0; kc < 4; ++kc) {
            v8bf bw = *(const v8bf*)(AT + (size_t)(ct * 16 + c) * D_ + kc * 32 + q * 8);
            acc = __builtin_amdgcn_mfma_f32_16x16x32_bf16(ahf[kc], bw, acc, 0, 0, 0);
        }
#pragma unroll
        for (int r = 0; r < 4; ++r) pw[q * 4 + r][ct * 16 + c] = acc[r];
    }
    __builtin_amdgcn_wave_barrier();
    {
        int row = lane >> 2, seg = lane & 3;
#pragma unroll
        for (int v = 0; v < 4; ++v) {
            v8bf gv;
#pragma unroll
            for (int j = 0; j < 8; ++j) gv[j] = (bf16_t)pw[row][seg * 32 + v * 8 + j];
            *(v8bf*)(gb + (size_t)(nrow0 + row) * D_ + seg * 32 + v * 8) = gv;
        }
    }
}

// ---------------------------------------------------------------------------
// k_att v4: exact round-0 structure (LDS transpose + 16B full-line Pt
// stores), single change: LDS staged in bf16 -> eb = 4x64x72x2B = 36.9 KB
// (was 68 KB f32). launch_bounds stays (256,2): r2 proved forcing 4
// waves/SIMD caps unified VGPR at 64 and spills the 128-VGPR A-frags to
// scratch (FETCH 82->352 MB). With natural allocation VGPR=112 <= 128, so
// HW can co-schedule 4 waves/SIMD AND 4 blocks/CU fit the 160 KiB LDS.
// ---------------------------------------------------------------------------
__global__ __launch_bounds__(256, 2) void k_att(
    const bf16_t* __restrict__ hb, const bf16_t* __restrict__ gb,
    const float* __restrict__ adj, float* __restrict__ colsum,
    bf16_t* __restrict__ Pt)
{
    int bid = blockIdx.x;
    int b = bid & 7;
    int rest = bid >> 3;          // 0..255
    int nblk = rest >> 3;         // 0..31
    int mgrp = rest & 7;          // 0..7
    int wave = threadIdx.x >> 6;
    int lane = threadIdx.x & 63;
    int q = lane >> 4;
    int c = lane & 15;
    int nbase = nblk * 64;
    int mwav = mgrp * 256 + wave * 64;
    const size_t hgoff = (size_t)b * N_ * D_;
    const float* adjb = adj + (size_t)b * N_ * N_;

    __shared__ bf16_t eb_all[4][64][72];
    bf16_t (*eb)[72] = eb_all[wave];

    // A-frags: 4 n-subtiles (persistent, 128 VGPRs)
    v8bf ag[4][4], ah[4][4];
#pragma unroll
    for (int sub = 0; sub < 4; ++sub)
#pragma unroll
        for (int kc = 0; kc < 4; ++kc) {
            size_t off = hgoff + (size_t)(nbase + sub * 16 + c) * D_ + kc * 32 + q * 8;
            ag[sub][kc] = *(const v8bf*)(gb + off);
            ah[sub][kc] = *(const v8bf*)(hb + off);
        }

    for (int t = 0; t < 4; ++t) {
        int mt = mwav + t * 16;
        // adj values: issue early, 16 independent 4B loads (full 64B lines)
        float av[4][4];
#pragma unroll
        for (int sub = 0; sub < 4; ++sub)
#pragma unroll
            for (int r = 0; r < 4; ++r)
                av[sub][r] = adjb[(size_t)(nbase + sub * 16 + q * 4 + r) * N_ + mt + c];
        // B-frags: 8 independent 16B loads
        v8bf bh[4], bg[4];
#pragma unroll
        for (int kc = 0; kc < 4; ++kc) {
            size_t off = hgoff + (size_t)(mt + c) * D_ + kc * 32 + q * 8;
            bh[kc] = *(const v8bf*)(hb + off);
            bg[kc] = *(const v8bf*)(gb + off);
        }
        v4f e[4];
#pragma unroll
        for (int sub = 0; sub < 4; ++sub) e[sub] = (v4f){0.f, 0.f, 0.f, 0.f};
#pragma unroll
        for (int kc = 0; kc < 4; ++kc)
#pragma unroll
            for (int sub = 0; sub < 4; ++sub) {
                e[sub] = __builtin_amdgcn_mfma_f32_16x16x32_bf16(ag[sub][kc], bh[kc], e[sub], 0, 0, 0);
                e[sub] = __builtin_amdgcn_mfma_f32_16x16x32_bf16(ah[sub][kc], bg[kc], e[sub], 0, 0, 0);
            }
        float cs = 0.f;
#pragma unroll
        for (int sub = 0; sub < 4; ++sub)
#pragma unroll
            for (int r = 0; r < 4; ++r) {
                float ex = __expf(e[sub][r]);
                float pv = (av[sub][r] > 0.f) ? ex : 0.f;
                eb[sub * 16 + q * 4 + r][t * 16 + c] = (bf16_t)pv;
                cs += pv;
            }
        cs += __shfl_xor(cs, 16);
        cs += __shfl_xor(cs, 32);
        if (lane < 16) atomicAdd(&colsum[b * N_ + mt + lane], cs);
    }
    __builtin_amdgcn_wave_barrier();
    // 64n x 64m bf16 tile -> coalesced 16B stores (full 64B lines)
    int prow = lane >> 3, pseg = lane & 7;
#pragma unroll
    for (int pass = 0; pass < 8; ++pass) {
        int row = pass * 8 + prow;
        v8bf o = *(const v8bf*)&eb[row][pseg * 8];
        *(v8bf*)(Pt + ((size_t)b * N_ + nbase + row) * N_ + mwav + pseg * 8) = o;
    }
}

// ---------------------------------------------------------------------------
// k_scaleT: hbTs[b][d][m] = h[b][m][d] * inv(colsum[b][m]).
// ---------------------------------------------------------------------------
__global__ __launch_bounds__(256) void k_scaleT(
    const bf16_t* __restrict__ hb, const float* __restrict__ colsum,
    bf16_t* __restrict__ hbTs)
{
    int bid = blockIdx.x;
    int b = bid >> 6;
    int rem = bid & 63;
    int nblk = rem >> 1;
    int dblk = rem & 1;
    int tid = threadIdx.x;
    __shared__ bf16_t sm[64][72];
    __shared__ float sinv[64];
    int n0 = nblk * 64, d0 = dblk * 64;
    int r = tid >> 3, cg = tid & 7;
#pragma unroll
    for (int rr = 0; rr < 2; ++rr) {
        int row = r + rr * 32;
        *(v8bf*)&sm[row][cg * 8] =
            *(const v8bf*)(hb + (size_t)(b * N_ + n0 + row) * D_ + d0 + cg * 8);
    }
    if (tid < 64) {
        float s = colsum[b * N_ + n0 + tid];
        sinv[tid] = (s > 0.f) ? 1.f / s : 0.f;
    }
    __syncthreads();
#pragma unroll
    for (int rr = 0; rr < 2; ++rr) {
        int dr = r + rr * 32;
        v8bf v;
#pragma unroll
        for (int jj = 0; jj < 8; ++jj)
            v[jj] = (bf16_t)((float)sm[cg * 8 + jj][dr] * sinv[cg * 8 + jj]);
        *(v8bf*)(hbTs + (size_t)(b * D_ + d0 + dr) * N_ + n0 + cg * 8) = v;
    }
}

// ---------------------------------------------------------------------------
// k_out: round-0 proven version. h_prime = Pt @ hbTs, fused epilogue.
// grid 256 (b=bid&7), 512 thr = 8 waves; wave w owns m-octant [w*256,+256).
// (r2's LDS-atomicAdd combine was ~64 us SLOWER than these serialized
// rounds — LDS atomic RMW contention. Keeping the proven combine.)
// ---------------------------------------------------------------------------
__global__ __launch_bounds__(512, 2) void k_out(
    const bf16_t* __restrict__ Pt, const bf16_t* __restrict__ hbTs,
    const float* __restrict__ x, const float* __restrict__ gw,
    const float* __restrict__ gbias, float* __restrict__ out)
{
    int bid = blockIdx.x;
    int b = bid & 7;
    int nblk = bid >> 3;          // 0..31
    int tid = threadIdx.x;
    int wave = tid >> 6;          // m-octant
    int lane = tid & 63;
    int q = lane >> 4;
    int c = lane & 15;
    int nbase = nblk * 64;
    int m0 = wave * 256;

    __shared__ float hp[64][132];

    const bf16_t* hTb = hbTs + (size_t)b * D_ * N_;
    const bf16_t* Pb  = Pt + (size_t)b * N_ * N_;

    v4f acc[4][8];
#pragma unroll
    for (int sub = 0; sub < 4; ++sub)
#pragma unroll
        for (int dt = 0; dt < 8; ++dt) acc[sub][dt] = (v4f){0.f, 0.f, 0.f, 0.f};

    for (int ch = 0; ch < 8; ++ch) {
        int mch = m0 + ch * 32;
        v8bf a[4];
#pragma unroll
        for (int sub = 0; sub < 4; ++sub)
            a[sub] = *(const v8bf*)(Pb + (size_t)(nbase + sub * 16 + c) * N_ + mch + q * 8);
        v8bf vt[8];
#pragma unroll
        for (int dt = 0; dt < 8; ++dt)
            vt[dt] = *(const v8bf*)(hTb + (size_t)(dt * 16 + c) * N_ + mch + q * 8);
#pragma unroll
        for (int dt = 0; dt < 8; ++dt)
#pragma unroll
            for (int sub = 0; sub < 4; ++sub)
                acc[sub][dt] = __builtin_amdgcn_mfma_f32_16x16x32_bf16(a[sub], vt[dt], acc[sub][dt], 0, 0, 0);
    }

    // combine the 8 m-octants in LDS
    if (wave == 0) {
#pragma unroll
        for (int sub = 0; sub < 4; ++sub)
#pragma unroll
            for (int dt = 0; dt < 8; ++dt)
#pragma unroll
                for (int r = 0; r < 4; ++r)
                    hp[sub * 16 + q * 4 + r][dt * 16 + c] = acc[sub][dt][r];
    }
    __syncthreads();
#pragma unroll
    for (int wv = 1; wv < 8; ++wv) {
        if (wave == wv) {
#pragma unroll
            for (int sub = 0; sub < 4; ++sub)
#pragma unroll
                for (int dt = 0; dt < 8; ++dt)
#pragma unroll
                    for (int r = 0; r < 4; ++r)
                        hp[sub * 16 + q * 4 + r][dt * 16 + c] += acc[sub][dt][r];
        }
        __syncthreads();
    }

    // fused epilogue: 512 thr = 64 rows x 8 segs x 16 d
    int row = tid >> 3;
    int seg = tid & 7;
    size_t g = (size_t)b * N_ + nbase + row;
    const float* xr = x + g * D_ + seg * 16;
    float xv[16], hv[16];
#pragma unroll
    for (int j = 0; j < 16; j += 4) {
        float4 f = *(const float4*)(xr + j);
        xv[j] = f.x; xv[j+1] = f.y; xv[j+2] = f.z; xv[j+3] = f.w;
    }
#pragma unroll
    for (int j = 0; j < 16; ++j) hv[j] = fmaxf(hp[row][seg * 16 + j], 0.f);
    float part = 0.f;
#pragma unroll
    for (int j = 0; j < 16; ++j)
        part += xv[j] * gw[seg * 16 + j] + hv[j] * gw[D_ + seg * 16 + j];
    part += __shfl_xor(part, 1);
    part += __shfl_xor(part, 2);
    part += __shfl_xor(part, 4);
    float coeff = 1.f / (1.f + __expf(-(part + gbias[0])));
    float* orow = out + g * D_ + seg * 16;
#pragma unroll
    for (int j = 0; j < 16; j += 4) {
        float4 o;
        o.x = coeff * xv[j]   + (1.f - coeff) * hv[j];
        o.y = coeff * xv[j+1] + (1.f - coeff) * hv[j+1];
        o.z = coeff * xv[j+2] + (1.f - coeff) * hv[j+2];
        o.w = coeff * xv[j+3] + (1.f - coeff) * hv[j+3];
        *(float4*)(orow + j) = o;
    }
}

// ---------------------------------------------------------------------------
extern "C" void kernel_launch(void* const* d_in, const int* in_sizes, int n_in,
                              void* d_out, int out_size, void* d_ws, size_t ws_size,
                              hipStream_t stream)
{
    const float* x     = (const float*)d_in[0];
    const float* adj   = (const float*)d_in[1];
    const float* Ww    = (const float*)d_in[2];
    const float* Wb    = (const float*)d_in[3];
    const float* Aw    = (const float*)d_in[4];
    const float* gw    = (const float*)d_in[5];
    const float* gbias = (const float*)d_in[6];
    float* out = (float*)d_out;

    char* ws = (char*)d_ws;
    bf16_t* hb     = (bf16_t*)(ws);                          // 4 MB
    bf16_t* gb     = (bf16_t*)(ws + (4 << 20));              // 4 MB
    bf16_t* hbTs   = (bf16_t*)(ws + (8 << 20));              // 4 MB
    float*  colsum = (float*)(ws + (12 << 20));              // 64 KB
    bf16_t* Pt     = (bf16_t*)(ws + (17 << 20));             // 64 MB
    bf16_t* WT     = (bf16_t*)(ws + (81 << 20));             // 32 KB
    bf16_t* AT     = (bf16_t*)(ws + (81 << 20) + (32 << 10));// 32 KB

    hipMemsetAsync(colsum, 0, B_ * N_ * sizeof(float), stream);
    k_prep<<<64, 256, 0, stream>>>(Ww, Aw, WT, AT);
    k_hg<<<B_ * N_ / 64, 256, 0, stream>>>(x, Wb, WT, AT, hb, gb);
    k_att<<<2048, 256, 0, stream>>>(hb, gb, adj, colsum, Pt);
    k_scaleT<<<512, 256, 0, stream>>>(hb, colsum, hbTs);
    k_out<<<256, 512, 0, stream>>>(Pt, hbTs, x, gw, gbias, out);
}